// Round 4
// baseline (785.022 us; speedup 1.0000x reference)
//
#include <hip/hip_runtime.h>
#include <stdint.h>

#define Bb 8
#define Tt 512
#define Vv 32000
#define Hh 1024
#define Ss 256
#define Ee 8
#define LEe 2
#define LMm 4
#define Mm (Bb*Tt)        // 4096
#define MKk (Bb*2*Tt)     // 8192

typedef unsigned short u16;
typedef __bf16 bf16x8 __attribute__((ext_vector_type(8)));
typedef float f32x4 __attribute__((ext_vector_type(4)));

__device__ __forceinline__ u16 f2bf(float f) {
  union { float f; uint32_t u; } c; c.f = f;
  uint32_t u = c.u;
  uint32_t r = (u + 0x7FFFu + ((u >> 16) & 1u)) >> 16;
  return (u16)r;
}

// ---------------------------------------------------------------------------
// 256x256 bf16 MFMA GEMM (head), 8-phase counted-vmcnt schedule (T3+T4+T5).
// BM=BN=256, BK=64 per K-tile, 2 K-tiles per loop iter, 8 waves (2M x 4N).
// LDS: per operand [2 buf][2 khalf][256 rows][32 cols] u16 = 64 KiB; 128 total.
// Phase p: 8 ds_read_b128 (one C-quadrant frags) + stage one 16KB K-half
//   (2 global_load_lds/thread) -> barrier -> lgkmcnt(0) -> 16 MFMA -> barrier.
// vmcnt(4) only at phases 4 and 8: 2 half-tiles allowed in flight, never 0.
// Stage ledger (iter t computes K-tiles 2t@buf0 ph1-4, 2t+1@buf1 ph5-8):
//   ph1:A-k1(2t+1)  ph2:B-k1(2t+1)  ph3:A-k0(2t+2)  ph4:B-k0(2t+2)
//   ph5:A-k1(2t+2)  ph6:B-k1(2t+2)  ph7:A-k0(2t+3)  ph8:B-k0(2t+3)
// Each slot restaged exactly 1 phase after its final read (barrier-separated);
// each read's data staged >=3 stage-positions before the governing vmcnt(4).
// ---------------------------------------------------------------------------
#define PHASE(cur, kh, mh, STAGECALL, WAITV)                                   \
  {                                                                            \
    bf16x8 af[4], bfr[4];                                                      \
    _Pragma("unroll")                                                          \
    for (int mi = 0; mi < 4; mi++)                                             \
      af[mi] = *(const bf16x8*)&As[cur][kh][(wr*128 + ((mh)*4+mi)*16 + l16)*32 + lhi*8]; \
    _Pragma("unroll")                                                          \
    for (int ni = 0; ni < 4; ni++)                                             \
      bfr[ni] = *(const bf16x8*)&Bs[cur][kh][(wc*64 + ni*16 + l16)*32 + lhi*8]; \
    STAGECALL;                                                                 \
    __builtin_amdgcn_sched_barrier(0);                                         \
    __builtin_amdgcn_s_barrier();                                              \
    asm volatile("s_waitcnt lgkmcnt(0)" ::: "memory");                         \
    __builtin_amdgcn_sched_barrier(0);                                         \
    __builtin_amdgcn_s_setprio(1);                                             \
    _Pragma("unroll")                                                          \
    for (int mi = 0; mi < 4; mi++)                                             \
      _Pragma("unroll")                                                        \
      for (int ni = 0; ni < 4; ni++)                                           \
        acc[(mh)*4+mi][ni] = __builtin_amdgcn_mfma_f32_16x16x32_bf16(af[mi], bfr[ni], acc[(mh)*4+mi][ni], 0, 0, 0); \
    __builtin_amdgcn_s_setprio(0);                                             \
    __builtin_amdgcn_sched_barrier(0);                                         \
    if (WAITV) { asm volatile("s_waitcnt vmcnt(4)" ::: "memory"); }            \
    __builtin_amdgcn_s_barrier();                                              \
    __builtin_amdgcn_sched_barrier(0);                                         \
  }

__global__ __launch_bounds__(512, 2)
void gemm256(const u16* __restrict__ A, const u16* __restrict__ Bw,
             int nbm, int N, int K, float* __restrict__ outF)
{
  __shared__ u16 As[2][2][256*32];
  __shared__ u16 Bs[2][2][256*32];

  const int id  = blockIdx.x;
  const int per = gridDim.x >> 3;
  const int vid = (id & 7) * per + (id >> 3);
  const int bm  = vid % nbm;
  const int bn  = vid / nbm;

  const int t = threadIdx.x;
  const int lane = t & 63;
  const int w = t >> 6;
  const int wr = w >> 2, wc = w & 3;        // 2 x 4 wave grid
  const int l16 = lane & 15, lhi = lane >> 4;

  const long long arow0 = (long long)bm * 256;
  const long long brow0 = (long long)bn * 256;

  // staging: K-half = 256 rows x 32 cols = 1024 16B-chunks; thread t does
  // chunks t and 512+t. chunk j: row j>>2, col-chunk j&3. LDS dest linear.
  long long aofs[2], bofs[2];
#pragma unroll
  for (int i = 0; i < 2; ++i) {
    const int r = i * 128 + (t >> 2);
    const int c = t & 3;
    aofs[i] = (arow0 + r) * (long long)K + c * 8;
    bofs[i] = (brow0 + r) * (long long)K + c * 8;
  }
  const int ldsd0 = t * 8, ldsd1 = (512 + t) * 8;

  f32x4 acc[8][4];
#pragma unroll
  for (int i = 0; i < 8; i++)
#pragma unroll
    for (int j = 0; j < 4; j++) acc[i][j] = (f32x4){0.f, 0.f, 0.f, 0.f};

  auto SA = [&](int b, int kh, int k0) {
    __builtin_amdgcn_global_load_lds(
        (const __attribute__((address_space(1))) void*)(A + aofs[0] + k0 + kh * 32),
        (__attribute__((address_space(3))) void*)(&As[b][kh][ldsd0]), 16, 0, 0);
    __builtin_amdgcn_global_load_lds(
        (const __attribute__((address_space(1))) void*)(A + aofs[1] + k0 + kh * 32),
        (__attribute__((address_space(3))) void*)(&As[b][kh][ldsd1]), 16, 0, 0);
  };
  auto SB = [&](int b, int kh, int k0) {
    __builtin_amdgcn_global_load_lds(
        (const __attribute__((address_space(1))) void*)(Bw + bofs[0] + k0 + kh * 32),
        (__attribute__((address_space(3))) void*)(&Bs[b][kh][ldsd0]), 16, 0, 0);
    __builtin_amdgcn_global_load_lds(
        (const __attribute__((address_space(1))) void*)(Bw + bofs[1] + k0 + kh * 32),
        (__attribute__((address_space(3))) void*)(&Bs[b][kh][ldsd1]), 16, 0, 0);
  };

  const int NT = K >> 6;                    // 16 K-tiles of BK=64

  // prologue: T0 fully, T1's k0 halves; allow T1-k0 pair in flight
  SA(0, 0, 0); SB(0, 0, 0); SA(0, 1, 0); SB(0, 1, 0);
  SA(1, 0, 64); SB(1, 0, 64);
  asm volatile("s_waitcnt vmcnt(4)" ::: "memory");
  __builtin_amdgcn_s_barrier();
  __builtin_amdgcn_sched_barrier(0);

  for (int it = 0; it < (NT >> 1); ++it) {
    const int k1 = (2 * it + 1) << 6;
    const int t2 = 2 * it + 2, t3 = 2 * it + 3;
    const int k2 = (t2 < NT ? t2 : NT - 1) << 6;
    const int k3 = (t3 < NT ? t3 : NT - 1) << 6;
    PHASE(0, 0, 0, SA(1, 1, k1), 0)
    PHASE(0, 0, 1, SB(1, 1, k1), 0)
    PHASE(0, 1, 0, SA(0, 0, k2), 0)
    PHASE(0, 1, 1, SB(0, 0, k2), 1)
    PHASE(1, 0, 0, SA(0, 1, k2), 0)
    PHASE(1, 0, 1, SB(0, 1, k2), 0)
    PHASE(1, 1, 0, SA(1, 0, k3), 0)
    PHASE(1, 1, 1, SB(1, 0, k3), 1)
  }

#pragma unroll
  for (int mi = 0; mi < 8; mi++) {
#pragma unroll
    for (int rr = 0; rr < 4; rr++) {
      const long long grow = arow0 + wr * 128 + mi * 16 + lhi * 4 + rr;
#pragma unroll
      for (int ni = 0; ni < 4; ni++) {
        const long long gcol = brow0 + wc * 64 + ni * 16 + l16;
        outF[grow * N + gcol] = acc[mi][ni][rr];
      }
    }
  }
}

// ---------------------------------------------------------------------------
// Tiled bf16 MFMA GEMM (small/mid): 128x128, BK=64, dbuf, swizzled.
// MODE 0: outB = bf16(silu(acc))
// MODE 1: outF = res + 0.1*acc (f32), outB = bf16(outF)
// MODE 2: outF = acc (f32)
// ---------------------------------------------------------------------------
template<int MODE>
__global__ __launch_bounds__(256, 2)
void gemm2(const u16* __restrict__ A, const u16* __restrict__ Bw,
           int nbm, int N, int K,
           const float* __restrict__ res, float* __restrict__ outF,
           u16* __restrict__ outB,
           const int* __restrict__ esel, long long estride)
{
  __shared__ u16 As[2][128*64];
  __shared__ u16 Bs[2][128*64];

  const int id  = blockIdx.x;
  const int per = gridDim.x >> 3;
  const int vid = (id & 7) * per + (id >> 3);
  const int bm  = vid % nbm;
  const int bn  = vid / nbm;

  const int t = threadIdx.x;
  const int w = t >> 6, lane = t & 63;
  const int wr = w >> 1, wc = w & 1;
  const int l16 = lane & 15, lhi = lane >> 4;

  const u16* Bp = Bw;
  if (esel) Bp += (long long)esel[bm >> 2] * estride;

  const long long arow0 = (long long)bm * 128;
  const long long brow0 = (long long)bn * 128;

  long long aoff[4], boff[4];
  int ldso[4];
#pragma unroll
  for (int i = 0; i < 4; ++i) {
    const int g  = i * 256 + t;
    const int r  = g >> 3;
    const int pc = g & 7;
    const int c  = pc ^ (r & 7);
    aoff[i] = (arow0 + r) * (long long)K + c * 8;
    boff[i] = (brow0 + r) * (long long)K + c * 8;
    ldso[i] = g * 8;
  }

  f32x4 acc[4][4];
#pragma unroll
  for (int i = 0; i < 4; i++)
#pragma unroll
    for (int j = 0; j < 4; j++) acc[i][j] = (f32x4){0.f, 0.f, 0.f, 0.f};

  auto STAGE = [&](int bsel, int k0) {
#pragma unroll
    for (int i = 0; i < 4; ++i)
      __builtin_amdgcn_global_load_lds(
          (const __attribute__((address_space(1))) void*)(A + aoff[i] + k0),
          (__attribute__((address_space(3))) void*)(&As[bsel][ldso[i]]), 16, 0, 0);
#pragma unroll
    for (int i = 0; i < 4; ++i)
      __builtin_amdgcn_global_load_lds(
          (const __attribute__((address_space(1))) void*)(Bp + boff[i] + k0),
          (__attribute__((address_space(3))) void*)(&Bs[bsel][ldso[i]]), 16, 0, 0);
  };

  const int rowA = (wr * 64 + l16) * 64;
  const int rowB = (wc * 64 + l16) * 64;
  const int x7   = l16 & 7;

  const int NT = K >> 6;

  STAGE(0, 0);
  asm volatile("s_waitcnt vmcnt(0)" ::: "memory");
  __builtin_amdgcn_s_barrier();
  __builtin_amdgcn_sched_barrier(0);

  for (int tile = 0; tile < NT; ++tile) {
    const int cur = tile & 1;
    if (tile + 1 < NT) STAGE(cur ^ 1, (tile + 1) << 6);

#pragma unroll
    for (int s = 0; s < 2; ++s) {
      bf16x8 af[4], bfr[4];
      const int swz = ((s * 4 + lhi) ^ x7) * 8;
#pragma unroll
      for (int mi = 0; mi < 4; mi++)
        af[mi] = *(const bf16x8*)&As[cur][rowA + mi * 1024 + swz];
#pragma unroll
      for (int ni = 0; ni < 4; ni++)
        bfr[ni] = *(const bf16x8*)&Bs[cur][rowB + ni * 1024 + swz];
      __builtin_amdgcn_s_setprio(1);
#pragma unroll
      for (int mi = 0; mi < 4; mi++)
#pragma unroll
        for (int ni = 0; ni < 4; ni++)
          acc[mi][ni] = __builtin_amdgcn_mfma_f32_16x16x32_bf16(af[mi], bfr[ni], acc[mi][ni], 0, 0, 0);
      __builtin_amdgcn_s_setprio(0);
    }

    if (tile + 1 < NT) {
      asm volatile("s_waitcnt vmcnt(0)" ::: "memory");
      __builtin_amdgcn_s_barrier();
      __builtin_amdgcn_sched_barrier(0);
    }
  }

#pragma unroll
  for (int mi = 0; mi < 4; mi++) {
#pragma unroll
    for (int rr = 0; rr < 4; rr++) {
      const long long grow = arow0 + wr * 64 + mi * 16 + lhi * 4 + rr;
#pragma unroll
      for (int ni = 0; ni < 4; ni++) {
        const long long gcol = brow0 + wc * 64 + ni * 16 + l16;
        const long long idx  = grow * N + gcol;
        float v = acc[mi][ni][rr];
        if (MODE == 0) {
          float s = v / (1.f + expf(-v));
          outB[idx] = f2bf(s);
        } else if (MODE == 1) {
          float o = res[idx] + 0.1f * v;
          outF[idx] = o;
          outB[idx] = f2bf(o);
        } else {
          outF[idx] = v;
        }
      }
    }
  }
}

// ---------------------------------------------------------------------------
// f32 -> bf16 plain convert (vectorized), n4 = #float4
__global__ void k_cvt(const float* __restrict__ in, u16* __restrict__ out, size_t n4) {
  size_t stride = (size_t)gridDim.x * blockDim.x;
  for (size_t i = (size_t)blockIdx.x * blockDim.x + threadIdx.x; i < n4; i += stride) {
    float4 v = ((const float4*)in)[i];
    ushort4 u;
    u.x = f2bf(v.x); u.y = f2bf(v.y); u.z = f2bf(v.z); u.w = f2bf(v.w);
    ((ushort4*)out)[i] = u;
  }
}

// LDS-tiled transpose-convert: in [b][R][C] f32 -> out [b][C][R] bf16
__global__ __launch_bounds__(256) void k_transpose(const float* __restrict__ in,
                                                   u16* __restrict__ out,
                                                   int R, int C) {
  __shared__ float tile[32][33];
  const int b  = blockIdx.z;
  const int c0 = blockIdx.x * 32, r0 = blockIdx.y * 32;
  const float* src = in  + (size_t)b * R * C;
  u16*         dst = out + (size_t)b * R * C;
  const int tx = threadIdx.x, ty = threadIdx.y;
#pragma unroll
  for (int i = 0; i < 4; ++i)
    tile[ty * 4 + i][tx] = src[(size_t)(r0 + ty * 4 + i) * C + c0 + tx];
  __syncthreads();
#pragma unroll
  for (int i = 0; i < 4; ++i)
    dst[(size_t)(c0 + ty * 4 + i) * R + r0 + tx] = f2bf(tile[tx][ty * 4 + i]);
}

// embedding gather: per-row copy, also emit bf16 copy
__global__ __launch_bounds__(256) void k_gather(const int* __restrict__ tokens,
                                                const float* __restrict__ embed,
                                                float* __restrict__ x, u16* __restrict__ xb) {
  int row = blockIdx.x, t = threadIdx.x;
  int tok = tokens[row];
  float4 v = ((const float4*)(embed + (size_t)tok * Hh))[t];
  ((float4*)(x + (size_t)row * Hh))[t] = v;
  ushort4 u;
  u.x = f2bf(v.x); u.y = f2bf(v.y); u.z = f2bf(v.z); u.w = f2bf(v.w);
  ((ushort4*)(xb + (size_t)row * Hh))[t] = u;
}

// column-mean stage 1
__global__ __launch_bounds__(1024) void k_cmean1(const float* __restrict__ x, float* __restrict__ part) {
  int b = blockIdx.x >> 3, ch = blockIdx.x & 7;
  int col = threadIdx.x;
  float s = 0.f;
  for (int t = ch * 64; t < ch * 64 + 64; ++t)
    s += x[((size_t)b * Tt + t) * Hh + col];
  part[(size_t)blockIdx.x * Hh + col] = s;
}
__global__ __launch_bounds__(1024) void k_cmean2(const float* __restrict__ part, float* __restrict__ xmean) {
  int b = blockIdx.x, col = threadIdx.x;
  float s = 0.f;
  for (int ch = 0; ch < 8; ch++) s += part[(size_t)(b * 8 + ch) * Hh + col];
  xmean[(size_t)b * Hh + col] = s * (1.f / (float)Tt);
}

// routing
__global__ __launch_bounds__(512) void k_route(const float* __restrict__ xmean,
                                               const float* __restrict__ rw,
                                               int* __restrict__ t2i, float* __restrict__ t2w) {
  int t = threadIdx.x;
  int b = t >> 6, lane = t & 63;
  float logits[Ee];
  for (int e = 0; e < Ee; e++) {
    float s = 0.f;
    for (int j = lane; j < Hh; j += 64)
      s += xmean[(size_t)b * Hh + j] * rw[(size_t)e * Hh + j];
    for (int off = 32; off; off >>= 1) s += __shfl_xor(s, off, 64);
    logits[e] = s * 2.f;
  }
  if (lane == 0) {
    float mx = logits[0];
    for (int e = 1; e < Ee; e++) mx = fmaxf(mx, logits[e]);
    float p[Ee], den = 0.f;
    for (int e = 0; e < Ee; e++) { p[e] = expf(logits[e] - mx); den += p[e]; }
    for (int e = 0; e < Ee; e++) p[e] /= den;
    int i1 = 0;
    for (int e = 1; e < Ee; e++) if (p[e] > p[i1]) i1 = e;
    int i2 = -1;
    for (int e = 0; e < Ee; e++) { if (e == i1) continue; if (i2 < 0 || p[e] > p[i2]) i2 = e; }
    float eb = expf(p[i2] - p[i1]);
    float w0 = 1.f / (1.f + eb);
    float w1 = eb / (1.f + eb);
    t2i[b * 2]     = i1;  t2i[b * 2 + 1] = i2;
    t2w[b * 2]     = w0;  t2w[b * 2 + 1] = w1;
  }
}

// broadcast x -> xk (k=0,1), both f32 and bf16
__global__ __launch_bounds__(256) void k_broadcast(const float* __restrict__ x, const u16* __restrict__ xb,
                                                   float* __restrict__ xk, u16* __restrict__ xkb) {
  int j = blockIdx.x, t = threadIdx.x;
  int b = j >> 10, tt = j & 511;
  int srow = b * Tt + tt;
  ((float4*)(xk + (size_t)j * Hh))[t] = ((const float4*)(x + (size_t)srow * Hh))[t];
  ((ushort4*)(xkb + (size_t)j * Hh))[t] = ((const ushort4*)(xb + (size_t)srow * Hh))[t];
}

// x += w0*xk[b,0] + w1*xk[b,1]
__global__ __launch_bounds__(256) void k_combine(float* __restrict__ x, const float* __restrict__ xk,
                                                 const float* __restrict__ w) {
  size_t i = (size_t)blockIdx.x * blockDim.x + threadIdx.x;
  size_t row = i >> 8;
  size_t col = i & 255;
  int b = (int)(row >> 9);
  int tt = (int)(row & 511);
  size_t r0 = ((size_t)b * 2) * Tt + tt;
  float w0 = w[b * 2], w1 = w[b * 2 + 1];
  float4 xv = ((const float4*)x)[i];
  float4 a = ((const float4*)xk)[r0 * 256 + col];
  float4 c = ((const float4*)xk)[(r0 + Tt) * 256 + col];
  float4 o;
  o.x = xv.x + w0 * a.x + w1 * c.x;
  o.y = xv.y + w0 * a.y + w1 * c.y;
  o.z = xv.z + w0 * a.z + w1 * c.z;
  o.w = xv.w + w0 * a.w + w1 * c.w;
  ((float4*)x)[i] = o;
}

// RMSNorm -> bf16
__global__ __launch_bounds__(256) void k_rmsnorm(const float* __restrict__ x, const float* __restrict__ nw,
                                                 u16* __restrict__ xnb) {
  int row = blockIdx.x, t = threadIdx.x;
  float4 v = ((const float4*)(x + (size_t)row * Hh))[t];
  float ss = v.x * v.x + v.y * v.y + v.z * v.z + v.w * v.w;
  for (int off = 32; off; off >>= 1) ss += __shfl_xor(ss, off, 64);
  __shared__ float red[4];
  if ((t & 63) == 0) red[t >> 6] = ss;
  __syncthreads();
  float tot = red[0] + red[1] + red[2] + red[3];
  float scale = rsqrtf(tot * (1.f / (float)Hh) + 1.1920928955078125e-07f);
  float4 w4 = ((const float4*)nw)[t];
  ushort4 u;
  u.x = f2bf(v.x * scale * w4.x);
  u.y = f2bf(v.y * scale * w4.y);
  u.z = f2bf(v.z * scale * w4.z);
  u.w = f2bf(v.w * scale * w4.w);
  ((ushort4*)(xnb + (size_t)row * Hh))[t] = u;
}

extern "C" void kernel_launch(void* const* d_in, const int* in_sizes, int n_in,
                              void* d_out, int out_size, void* d_ws, size_t ws_size,
                              hipStream_t stream) {
  const int*   tokens = (const int*)d_in[0];
  const float* embed  = (const float*)d_in[1];
  const float* rw     = (const float*)d_in[2];
  const float* bw1    = (const float*)d_in[3];
  const float* bw2    = (const float*)d_in[4];
  const float* ew1    = (const float*)d_in[5];
  const float* ew2    = (const float*)d_in[6];
  const float* nw     = (const float*)d_in[7];
  const float* hw     = (const float*)d_in[8];
  float* out = (float*)d_out;

  char* p = (char*)d_ws;
  auto nxt = [&](size_t bytes) { char* r = p; p += (bytes + 255) & ~(size_t)255; return r; };
  float* x    = (float*)nxt((size_t)Mm * Hh * 4);
  u16*   xb   = (u16*)  nxt((size_t)Mm * Hh * 2);
  float* xk   = (float*)nxt((size_t)MKk * Hh * 4);
  u16*   xkb  = (u16*)  nxt((size_t)MKk * Hh * 2);
  u16*   hbuf = (u16*)  nxt((size_t)MKk * Ss * 2);
  u16*   w1t  = (u16*)  nxt((size_t)LMm * Ss * Hh * 2);
  u16*   w2t  = (u16*)  nxt((size_t)LMm * Hh * Ss * 2);
  u16*   e1t  = (u16*)  nxt((size_t)Ee * LEe * Ss * Hh * 2);
  u16*   e2t  = (u16*)  nxt((size_t)Ee * LEe * Hh * Ss * 2);
  u16*   hwb  = (u16*)  nxt((size_t)Vv * Hh * 2);
  float* part = (float*)nxt((size_t)64 * Hh * 4);
  float* xmean= (float*)nxt((size_t)Bb * Hh * 4);
  int*   t2i  = (int*)  nxt(16 * 4);
  float* t2w  = (float*)nxt(16 * 4);

  // weight conversions
  k_cvt<<<2048, 256, 0, stream>>>(hw, hwb, (size_t)Vv * Hh / 4);
  k_transpose<<<dim3(Ss/32, Hh/32, LMm), dim3(32,8), 0, stream>>>(bw1, w1t, Hh, Ss);
  k_transpose<<<dim3(Hh/32, Ss/32, LMm), dim3(32,8), 0, stream>>>(bw2, w2t, Ss, Hh);
  k_transpose<<<dim3(Ss/32, Hh/32, Ee*LEe), dim3(32,8), 0, stream>>>(ew1, e1t, Hh, Ss);
  k_transpose<<<dim3(Hh/32, Ss/32, Ee*LEe), dim3(32,8), 0, stream>>>(ew2, e2t, Ss, Hh);

  // embed gather + routing
  k_gather<<<Mm, 256, 0, stream>>>(tokens, embed, x, xb);
  k_cmean1<<<64, 1024, 0, stream>>>(x, part);
  k_cmean2<<<Bb, 1024, 0, stream>>>(part, xmean);
  k_route<<<1, 512, 0, stream>>>(xmean, rw, t2i, t2w);

  // backbone micro-layers
  for (int l = 0; l < LMm; l++) {
    gemm2<0><<<(Mm/128)*(Ss/128), 256, 0, stream>>>(xb, w1t + (size_t)l * Ss * Hh,
        Mm/128, Ss, Hh, nullptr, nullptr, hbuf, nullptr, 0);
    gemm2<1><<<(Mm/128)*(Hh/128), 256, 0, stream>>>(hbuf, w2t + (size_t)l * Hh * Ss,
        Mm/128, Hh, Ss, x, x, xb, nullptr, 0);
  }

  // expert path
  k_broadcast<<<MKk, 256, 0, stream>>>(x, xb, xk, xkb);
  for (int l = 0; l < LEe; l++) {
    gemm2<0><<<(MKk/128)*(Ss/128), 256, 0, stream>>>(xkb, e1t + (size_t)l * Ss * Hh,
        MKk/128, Ss, Hh, nullptr, nullptr, hbuf, t2i, (long long)LEe * Ss * Hh);
    gemm2<1><<<(MKk/128)*(Hh/128), 256, 0, stream>>>(hbuf, e2t + (size_t)l * Hh * Ss,
        MKk/128, Hh, Ss, xk, xk, xkb, t2i, (long long)LEe * Hh * Ss);
  }
  k_combine<<<Mm, 256, 0, stream>>>(x, xk, t2w);

  // RMSNorm -> bf16, then head GEMM (8-phase 256^2)
  k_rmsnorm<<<Mm, 256, 0, stream>>>(x, nw, xb);
  gemm256<<<(Mm/256)*(Vv/256), 512, 0, stream>>>(xb, hwb, Mm/256, Vv, Hh, out);
}

// Round 5
// 730.308 us; speedup vs baseline: 1.0749x; 1.0749x over previous
//
#include <hip/hip_runtime.h>
#include <stdint.h>

#define Bb 8
#define Tt 512
#define Vv 32000
#define Hh 1024
#define Ss 256
#define Ee 8
#define LEe 2
#define LMm 4
#define Mm (Bb*Tt)        // 4096
#define MKk (Bb*2*Tt)     // 8192

typedef unsigned short u16;
typedef __bf16 bf16x8 __attribute__((ext_vector_type(8)));
typedef float f32x4 __attribute__((ext_vector_type(4)));

__device__ __forceinline__ u16 f2bf(float f) {
  union { float f; uint32_t u; } c; c.f = f;
  uint32_t u = c.u;
  uint32_t r = (u + 0x7FFFu + ((u >> 16) & 1u)) >> 16;
  return (u16)r;
}

// ---------------------------------------------------------------------------
// 256x256 bf16 MFMA GEMM (head), 8-phase counted-vmcnt schedule (T2+T3+T4+T5).
// BM=BN=256, BK=64/K-tile, 2 K-tiles/iter, 8 waves (2M x 4N).
// LDS per operand: [2 buf][2 khalf][256 rows][32 cols] u16 (16 KB slots).
// Swizzle (T2): logical chunk c (16B) of row r stored at physical c^((r>>1)&3)
//   -> quarter-wave ds_read_b128 hits 8 distinct 16B bank slots x 2 lanes
//   (2-way = free). Applied on BOTH stage-source and read offsets.
// Phases (per K-tile, kh outer, mh inner; bfr cached across mh -> B read 1x):
//   P(kh,0): read a[0..3],b[0..3] (8 rds)  -> 16 MFMA (mh=0)
//   P(kh,1): read a[4..7] (4 rds)          -> 16 MFMA (mh=1, cached b)
// Stage 1 half-slot (2 global_load_lds/thread) per phase; vmcnt(4) only at
// phases 4 and 8 (2 half-slots in flight, never drained to 0).
// Ledger (iter it: tiles 2it@buf0 P1-4, 2it+1@buf1 P5-8):
//   P1:SA(b1,k1,t1) P2:SB(b1,k1,t1) P3:SA(b0,k0,t2) P4:SB(b0,k0,t2)+W
//   P5:SA(b0,k1,t2) P6:SB(b0,k1,t2) P7:SA(b1,k0,t3) P8:SB(b1,k0,t3)+W
// Every slot restaged >=1 barrier-separated phase after its last read; every
// read's stage retired by the governing vmcnt(4) (verified by count).
// ---------------------------------------------------------------------------
#define PHASE(cur, kh, mh, READB, STAGECALL, WAITV)                            \
  {                                                                            \
    bf16x8 af[4];                                                              \
    _Pragma("unroll")                                                          \
    for (int mi = 0; mi < 4; mi++)                                             \
      af[mi] = *(const bf16x8*)&As[cur][kh][aoffs[(mh)*4 + mi]];               \
    if (READB) {                                                               \
      _Pragma("unroll")                                                        \
      for (int ni = 0; ni < 4; ni++)                                           \
        bfr[ni] = *(const bf16x8*)&Bs[cur][kh][boffs[ni]];                     \
    }                                                                          \
    STAGECALL;                                                                 \
    __builtin_amdgcn_sched_barrier(0);                                         \
    __builtin_amdgcn_s_barrier();                                              \
    asm volatile("s_waitcnt lgkmcnt(0)" ::: "memory");                         \
    __builtin_amdgcn_sched_barrier(0);                                         \
    __builtin_amdgcn_s_setprio(1);                                             \
    _Pragma("unroll")                                                          \
    for (int mi = 0; mi < 4; mi++)                                             \
      _Pragma("unroll")                                                        \
      for (int ni = 0; ni < 4; ni++)                                           \
        acc[(mh)*4+mi][ni] = __builtin_amdgcn_mfma_f32_16x16x32_bf16(af[mi], bfr[ni], acc[(mh)*4+mi][ni], 0, 0, 0); \
    __builtin_amdgcn_s_setprio(0);                                             \
    __builtin_amdgcn_sched_barrier(0);                                         \
    if (WAITV) { asm volatile("s_waitcnt vmcnt(4)" ::: "memory"); }            \
    __builtin_amdgcn_s_barrier();                                              \
    __builtin_amdgcn_sched_barrier(0);                                         \
  }

__global__ __launch_bounds__(512, 2)
void gemm256(const u16* __restrict__ A, const u16* __restrict__ Bw,
             int nbm, int N, int K, float* __restrict__ outF)
{
  __shared__ u16 As[2][2][256*32];
  __shared__ u16 Bs[2][2][256*32];

  const int id  = blockIdx.x;
  const int per = gridDim.x >> 3;
  const int vid = (id & 7) * per + (id >> 3);
  const int bm  = vid % nbm;
  const int bn  = vid / nbm;

  const int t = threadIdx.x;
  const int lane = t & 63;
  const int w = t >> 6;
  const int wr = w >> 2, wc = w & 3;        // 2 x 4 wave grid
  const int l16 = lane & 15, lhi = lane >> 4;

  const long long arow0 = (long long)bm * 256;
  const long long brow0 = (long long)bn * 256;

  // swizzled read offsets (u16 units) into a [256][32] slot
  int aoffs[8], boffs[4];
#pragma unroll
  for (int mi = 0; mi < 8; mi++) {
    const int r = wr * 128 + mi * 16 + l16;
    aoffs[mi] = r * 32 + (lhi ^ ((r >> 1) & 3)) * 8;
  }
#pragma unroll
  for (int ni = 0; ni < 4; ni++) {
    const int r = wc * 64 + ni * 16 + l16;
    boffs[ni] = r * 32 + (lhi ^ ((r >> 1) & 3)) * 8;
  }

  // staging: half-slot = 1024 16B-chunks; thread t does chunks t and 512+t.
  // LDS chunk g (row r=g>>2, phys pc=g&3) holds logical chunk pc^((r>>1)&3).
  long long sA[2], sB[2];
  int ldsd[2];
#pragma unroll
  for (int i = 0; i < 2; ++i) {
    const int g = i * 512 + t;
    const int r = g >> 2;
    const int c = (g & 3) ^ ((r >> 1) & 3);
    sA[i] = (arow0 + r) * (long long)K + c * 8;
    sB[i] = (brow0 + r) * (long long)K + c * 8;
    ldsd[i] = g * 8;
  }

  f32x4 acc[8][4];
#pragma unroll
  for (int i = 0; i < 8; i++)
#pragma unroll
    for (int j = 0; j < 4; j++) acc[i][j] = (f32x4){0.f, 0.f, 0.f, 0.f};

  auto SA = [&](int b, int kh, int k0) {
#pragma unroll
    for (int i = 0; i < 2; ++i)
      __builtin_amdgcn_global_load_lds(
          (const __attribute__((address_space(1))) void*)(A + sA[i] + k0 + kh * 32),
          (__attribute__((address_space(3))) void*)(&As[b][kh][ldsd[i]]), 16, 0, 0);
  };
  auto SB = [&](int b, int kh, int k0) {
#pragma unroll
    for (int i = 0; i < 2; ++i)
      __builtin_amdgcn_global_load_lds(
          (const __attribute__((address_space(1))) void*)(Bw + sB[i] + k0 + kh * 32),
          (__attribute__((address_space(3))) void*)(&Bs[b][kh][ldsd[i]]), 16, 0, 0);
  };

  bf16x8 bfr[4];

  const int NT = K >> 6;                    // 16 K-tiles of BK=64

  // prologue: T0 fully, T1's kh0; leaves T1-kh0 (4 loads) in flight
  SA(0, 0, 0); SB(0, 0, 0); SA(0, 1, 0); SB(0, 1, 0);
  SA(1, 0, 64); SB(1, 0, 64);
  asm volatile("s_waitcnt vmcnt(4)" ::: "memory");
  __builtin_amdgcn_s_barrier();
  __builtin_amdgcn_sched_barrier(0);

  for (int it = 0; it < (NT >> 1); ++it) {
    const int k1 = (2 * it + 1) << 6;
    const int t2 = 2 * it + 2, t3 = 2 * it + 3;
    const int k2 = (t2 < NT ? t2 : NT - 1) << 6;
    const int k3 = (t3 < NT ? t3 : NT - 1) << 6;
    PHASE(0, 0, 0, 1, SA(1, 1, k1), 0)
    PHASE(0, 0, 1, 0, SB(1, 1, k1), 0)
    PHASE(0, 1, 0, 1, SA(0, 0, k2), 0)
    PHASE(0, 1, 1, 0, SB(0, 0, k2), 1)
    PHASE(1, 0, 0, 1, SA(0, 1, k2), 0)
    PHASE(1, 0, 1, 0, SB(0, 1, k2), 0)
    PHASE(1, 1, 0, 1, SA(1, 0, k3), 0)
    PHASE(1, 1, 1, 0, SB(1, 0, k3), 1)
  }

#pragma unroll
  for (int mi = 0; mi < 8; mi++) {
#pragma unroll
    for (int rr = 0; rr < 4; rr++) {
      const long long grow = arow0 + wr * 128 + mi * 16 + lhi * 4 + rr;
#pragma unroll
      for (int ni = 0; ni < 4; ni++) {
        const long long gcol = brow0 + wc * 64 + ni * 16 + l16;
        outF[grow * N + gcol] = acc[mi][ni][rr];
      }
    }
  }
}

// ---------------------------------------------------------------------------
// Tiled bf16 MFMA GEMM (small/mid): 128x128, BK=64, dbuf, swizzled.
// MODE 0: outB = bf16(silu(acc))
// MODE 1: outF = res + 0.1*acc (f32), outB = bf16(outF)
// MODE 2: outF = acc (f32)
// ---------------------------------------------------------------------------
template<int MODE>
__global__ __launch_bounds__(256, 2)
void gemm2(const u16* __restrict__ A, const u16* __restrict__ Bw,
           int nbm, int N, int K,
           const float* __restrict__ res, float* __restrict__ outF,
           u16* __restrict__ outB,
           const int* __restrict__ esel, long long estride)
{
  __shared__ u16 As[2][128*64];
  __shared__ u16 Bs[2][128*64];

  const int id  = blockIdx.x;
  const int per = gridDim.x >> 3;
  const int vid = (id & 7) * per + (id >> 3);
  const int bm  = vid % nbm;
  const int bn  = vid / nbm;

  const int t = threadIdx.x;
  const int w = t >> 6, lane = t & 63;
  const int wr = w >> 1, wc = w & 1;
  const int l16 = lane & 15, lhi = lane >> 4;

  const u16* Bp = Bw;
  if (esel) Bp += (long long)esel[bm >> 2] * estride;

  const long long arow0 = (long long)bm * 128;
  const long long brow0 = (long long)bn * 128;

  long long aoff[4], boff[4];
  int ldso[4];
#pragma unroll
  for (int i = 0; i < 4; ++i) {
    const int g  = i * 256 + t;
    const int r  = g >> 3;
    const int pc = g & 7;
    const int c  = pc ^ (r & 7);
    aoff[i] = (arow0 + r) * (long long)K + c * 8;
    boff[i] = (brow0 + r) * (long long)K + c * 8;
    ldso[i] = g * 8;
  }

  f32x4 acc[4][4];
#pragma unroll
  for (int i = 0; i < 4; i++)
#pragma unroll
    for (int j = 0; j < 4; j++) acc[i][j] = (f32x4){0.f, 0.f, 0.f, 0.f};

  auto STAGE = [&](int bsel, int k0) {
#pragma unroll
    for (int i = 0; i < 4; ++i)
      __builtin_amdgcn_global_load_lds(
          (const __attribute__((address_space(1))) void*)(A + aoff[i] + k0),
          (__attribute__((address_space(3))) void*)(&As[bsel][ldso[i]]), 16, 0, 0);
#pragma unroll
    for (int i = 0; i < 4; ++i)
      __builtin_amdgcn_global_load_lds(
          (const __attribute__((address_space(1))) void*)(Bp + boff[i] + k0),
          (__attribute__((address_space(3))) void*)(&Bs[bsel][ldso[i]]), 16, 0, 0);
  };

  const int rowA = (wr * 64 + l16) * 64;
  const int rowB = (wc * 64 + l16) * 64;
  const int x7   = l16 & 7;

  const int NT = K >> 6;

  STAGE(0, 0);
  asm volatile("s_waitcnt vmcnt(0)" ::: "memory");
  __builtin_amdgcn_s_barrier();
  __builtin_amdgcn_sched_barrier(0);

  for (int tile = 0; tile < NT; ++tile) {
    const int cur = tile & 1;
    if (tile + 1 < NT) STAGE(cur ^ 1, (tile + 1) << 6);

#pragma unroll
    for (int s = 0; s < 2; ++s) {
      bf16x8 af[4], bfr[4];
      const int swz = ((s * 4 + lhi) ^ x7) * 8;
#pragma unroll
      for (int mi = 0; mi < 4; mi++)
        af[mi] = *(const bf16x8*)&As[cur][rowA + mi * 1024 + swz];
#pragma unroll
      for (int ni = 0; ni < 4; ni++)
        bfr[ni] = *(const bf16x8*)&Bs[cur][rowB + ni * 1024 + swz];
      __builtin_amdgcn_s_setprio(1);
#pragma unroll
      for (int mi = 0; mi < 4; mi++)
#pragma unroll
        for (int ni = 0; ni < 4; ni++)
          acc[mi][ni] = __builtin_amdgcn_mfma_f32_16x16x32_bf16(af[mi], bfr[ni], acc[mi][ni], 0, 0, 0);
      __builtin_amdgcn_s_setprio(0);
    }

    if (tile + 1 < NT) {
      asm volatile("s_waitcnt vmcnt(0)" ::: "memory");
      __builtin_amdgcn_s_barrier();
      __builtin_amdgcn_sched_barrier(0);
    }
  }

#pragma unroll
  for (int mi = 0; mi < 4; mi++) {
#pragma unroll
    for (int rr = 0; rr < 4; rr++) {
      const long long grow = arow0 + wr * 64 + mi * 16 + lhi * 4 + rr;
#pragma unroll
      for (int ni = 0; ni < 4; ni++) {
        const long long gcol = brow0 + wc * 64 + ni * 16 + l16;
        const long long idx  = grow * N + gcol;
        float v = acc[mi][ni][rr];
        if (MODE == 0) {
          float s = v / (1.f + expf(-v));
          outB[idx] = f2bf(s);
        } else if (MODE == 1) {
          float o = res[idx] + 0.1f * v;
          outF[idx] = o;
          outB[idx] = f2bf(o);
        } else {
          outF[idx] = v;
        }
      }
    }
  }
}

// ---------------------------------------------------------------------------
// f32 -> bf16 plain convert (vectorized), n4 = #float4
__global__ void k_cvt(const float* __restrict__ in, u16* __restrict__ out, size_t n4) {
  size_t stride = (size_t)gridDim.x * blockDim.x;
  for (size_t i = (size_t)blockIdx.x * blockDim.x + threadIdx.x; i < n4; i += stride) {
    float4 v = ((const float4*)in)[i];
    ushort4 u;
    u.x = f2bf(v.x); u.y = f2bf(v.y); u.z = f2bf(v.z); u.w = f2bf(v.w);
    ((ushort4*)out)[i] = u;
  }
}

// LDS-tiled transpose-convert: in [b][R][C] f32 -> out [b][C][R] bf16
__global__ __launch_bounds__(256) void k_transpose(const float* __restrict__ in,
                                                   u16* __restrict__ out,
                                                   int R, int C) {
  __shared__ float tile[32][33];
  const int b  = blockIdx.z;
  const int c0 = blockIdx.x * 32, r0 = blockIdx.y * 32;
  const float* src = in  + (size_t)b * R * C;
  u16*         dst = out + (size_t)b * R * C;
  const int tx = threadIdx.x, ty = threadIdx.y;
#pragma unroll
  for (int i = 0; i < 4; ++i)
    tile[ty * 4 + i][tx] = src[(size_t)(r0 + ty * 4 + i) * C + c0 + tx];
  __syncthreads();
#pragma unroll
  for (int i = 0; i < 4; ++i)
    dst[(size_t)(c0 + ty * 4 + i) * R + r0 + tx] = f2bf(tile[tx][ty * 4 + i]);
}

// embedding gather: per-row copy, also emit bf16 copy
__global__ __launch_bounds__(256) void k_gather(const int* __restrict__ tokens,
                                                const float* __restrict__ embed,
                                                float* __restrict__ x, u16* __restrict__ xb) {
  int row = blockIdx.x, t = threadIdx.x;
  int tok = tokens[row];
  float4 v = ((const float4*)(embed + (size_t)tok * Hh))[t];
  ((float4*)(x + (size_t)row * Hh))[t] = v;
  ushort4 u;
  u.x = f2bf(v.x); u.y = f2bf(v.y); u.z = f2bf(v.z); u.w = f2bf(v.w);
  ((ushort4*)(xb + (size_t)row * Hh))[t] = u;
}

// column-mean stage 1
__global__ __launch_bounds__(1024) void k_cmean1(const float* __restrict__ x, float* __restrict__ part) {
  int b = blockIdx.x >> 3, ch = blockIdx.x & 7;
  int col = threadIdx.x;
  float s = 0.f;
  for (int t = ch * 64; t < ch * 64 + 64; ++t)
    s += x[((size_t)b * Tt + t) * Hh + col];
  part[(size_t)blockIdx.x * Hh + col] = s;
}
__global__ __launch_bounds__(1024) void k_cmean2(const float* __restrict__ part, float* __restrict__ xmean) {
  int b = blockIdx.x, col = threadIdx.x;
  float s = 0.f;
  for (int ch = 0; ch < 8; ch++) s += part[(size_t)(b * 8 + ch) * Hh + col];
  xmean[(size_t)b * Hh + col] = s * (1.f / (float)Tt);
}

// routing
__global__ __launch_bounds__(512) void k_route(const float* __restrict__ xmean,
                                               const float* __restrict__ rw,
                                               int* __restrict__ t2i, float* __restrict__ t2w) {
  int t = threadIdx.x;
  int b = t >> 6, lane = t & 63;
  float logits[Ee];
  for (int e = 0; e < Ee; e++) {
    float s = 0.f;
    for (int j = lane; j < Hh; j += 64)
      s += xmean[(size_t)b * Hh + j] * rw[(size_t)e * Hh + j];
    for (int off = 32; off; off >>= 1) s += __shfl_xor(s, off, 64);
    logits[e] = s * 2.f;
  }
  if (lane == 0) {
    float mx = logits[0];
    for (int e = 1; e < Ee; e++) mx = fmaxf(mx, logits[e]);
    float p[Ee], den = 0.f;
    for (int e = 0; e < Ee; e++) { p[e] = expf(logits[e] - mx); den += p[e]; }
    for (int e = 0; e < Ee; e++) p[e] /= den;
    int i1 = 0;
    for (int e = 1; e < Ee; e++) if (p[e] > p[i1]) i1 = e;
    int i2 = -1;
    for (int e = 0; e < Ee; e++) { if (e == i1) continue; if (i2 < 0 || p[e] > p[i2]) i2 = e; }
    float eb = expf(p[i2] - p[i1]);
    float w0 = 1.f / (1.f + eb);
    float w1 = eb / (1.f + eb);
    t2i[b * 2]     = i1;  t2i[b * 2 + 1] = i2;
    t2w[b * 2]     = w0;  t2w[b * 2 + 1] = w1;
  }
}

// broadcast x -> xk (k=0,1), both f32 and bf16
__global__ __launch_bounds__(256) void k_broadcast(const float* __restrict__ x, const u16* __restrict__ xb,
                                                   float* __restrict__ xk, u16* __restrict__ xkb) {
  int j = blockIdx.x, t = threadIdx.x;
  int b = j >> 10, tt = j & 511;
  int srow = b * Tt + tt;
  ((float4*)(xk + (size_t)j * Hh))[t] = ((const float4*)(x + (size_t)srow * Hh))[t];
  ((ushort4*)(xkb + (size_t)j * Hh))[t] = ((const ushort4*)(xb + (size_t)srow * Hh))[t];
}

// x += w0*xk[b,0] + w1*xk[b,1]
__global__ __launch_bounds__(256) void k_combine(float* __restrict__ x, const float* __restrict__ xk,
                                                 const float* __restrict__ w) {
  size_t i = (size_t)blockIdx.x * blockDim.x + threadIdx.x;
  size_t row = i >> 8;
  size_t col = i & 255;
  int b = (int)(row >> 9);
  int tt = (int)(row & 511);
  size_t r0 = ((size_t)b * 2) * Tt + tt;
  float w0 = w[b * 2], w1 = w[b * 2 + 1];
  float4 xv = ((const float4*)x)[i];
  float4 a = ((const float4*)xk)[r0 * 256 + col];
  float4 c = ((const float4*)xk)[(r0 + Tt) * 256 + col];
  float4 o;
  o.x = xv.x + w0 * a.x + w1 * c.x;
  o.y = xv.y + w0 * a.y + w1 * c.y;
  o.z = xv.z + w0 * a.z + w1 * c.z;
  o.w = xv.w + w0 * a.w + w1 * c.w;
  ((float4*)x)[i] = o;
}

// RMSNorm -> bf16
__global__ __launch_bounds__(256) void k_rmsnorm(const float* __restrict__ x, const float* __restrict__ nw,
                                                 u16* __restrict__ xnb) {
  int row = blockIdx.x, t = threadIdx.x;
  float4 v = ((const float4*)(x + (size_t)row * Hh))[t];
  float ss = v.x * v.x + v.y * v.y + v.z * v.z + v.w * v.w;
  for (int off = 32; off; off >>= 1) ss += __shfl_xor(ss, off, 64);
  __shared__ float red[4];
  if ((t & 63) == 0) red[t >> 6] = ss;
  __syncthreads();
  float tot = red[0] + red[1] + red[2] + red[3];
  float scale = rsqrtf(tot * (1.f / (float)Hh) + 1.1920928955078125e-07f);
  float4 w4 = ((const float4*)nw)[t];
  ushort4 u;
  u.x = f2bf(v.x * scale * w4.x);
  u.y = f2bf(v.y * scale * w4.y);
  u.z = f2bf(v.z * scale * w4.z);
  u.w = f2bf(v.w * scale * w4.w);
  ((ushort4*)(xnb + (size_t)row * Hh))[t] = u;
}

extern "C" void kernel_launch(void* const* d_in, const int* in_sizes, int n_in,
                              void* d_out, int out_size, void* d_ws, size_t ws_size,
                              hipStream_t stream) {
  const int*   tokens = (const int*)d_in[0];
  const float* embed  = (const float*)d_in[1];
  const float* rw     = (const float*)d_in[2];
  const float* bw1    = (const float*)d_in[3];
  const float* bw2    = (const float*)d_in[4];
  const float* ew1    = (const float*)d_in[5];
  const float* ew2    = (const float*)d_in[6];
  const float* nw     = (const float*)d_in[7];
  const float* hw     = (const float*)d_in[8];
  float* out = (float*)d_out;

  char* p = (char*)d_ws;
  auto nxt = [&](size_t bytes) { char* r = p; p += (bytes + 255) & ~(size_t)255; return r; };
  float* x    = (float*)nxt((size_t)Mm * Hh * 4);
  u16*   xb   = (u16*)  nxt((size_t)Mm * Hh * 2);
  float* xk   = (float*)nxt((size_t)MKk * Hh * 4);
  u16*   xkb  = (u16*)  nxt((size_t)MKk * Hh * 2);
  u16*   hbuf = (u16*)  nxt((size_t)MKk * Ss * 2);
  u16*   w1t  = (u16*)  nxt((size_t)LMm * Ss * Hh * 2);
  u16*   w2t  = (u16*)  nxt((size_t)LMm * Hh * Ss * 2);
  u16*   e1t  = (u16*)  nxt((size_t)Ee * LEe * Ss * Hh * 2);
  u16*   e2t  = (u16*)  nxt((size_t)Ee * LEe * Hh * Ss * 2);
  u16*   hwb  = (u16*)  nxt((size_t)Vv * Hh * 2);
  float* part = (float*)nxt((size_t)64 * Hh * 4);
  float* xmean= (float*)nxt((size_t)Bb * Hh * 4);
  int*   t2i  = (int*)  nxt(16 * 4);
  float* t2w  = (float*)nxt(16 * 4);

  // weight conversions
  k_cvt<<<2048, 256, 0, stream>>>(hw, hwb, (size_t)Vv * Hh / 4);
  k_transpose<<<dim3(Ss/32, Hh/32, LMm), dim3(32,8), 0, stream>>>(bw1, w1t, Hh, Ss);
  k_transpose<<<dim3(Hh/32, Ss/32, LMm), dim3(32,8), 0, stream>>>(bw2, w2t, Ss, Hh);
  k_transpose<<<dim3(Ss/32, Hh/32, Ee*LEe), dim3(32,8), 0, stream>>>(ew1, e1t, Hh, Ss);
  k_transpose<<<dim3(Hh/32, Ss/32, Ee*LEe), dim3(32,8), 0, stream>>>(ew2, e2t, Ss, Hh);

  // embed gather + routing
  k_gather<<<Mm, 256, 0, stream>>>(tokens, embed, x, xb);
  k_cmean1<<<64, 1024, 0, stream>>>(x, part);
  k_cmean2<<<Bb, 1024, 0, stream>>>(part, xmean);
  k_route<<<1, 512, 0, stream>>>(xmean, rw, t2i, t2w);

  // backbone micro-layers
  for (int l = 0; l < LMm; l++) {
    gemm2<0><<<(Mm/128)*(Ss/128), 256, 0, stream>>>(xb, w1t + (size_t)l * Ss * Hh,
        Mm/128, Ss, Hh, nullptr, nullptr, hbuf, nullptr, 0);
    gemm2<1><<<(Mm/128)*(Hh/128), 256, 0, stream>>>(hbuf, w2t + (size_t)l * Hh * Ss,
        Mm/128, Hh, Ss, x, x, xb, nullptr, 0);
  }

  // expert path
  k_broadcast<<<MKk, 256, 0, stream>>>(x, xb, xk, xkb);
  for (int l = 0; l < LEe; l++) {
    gemm2<0><<<(MKk/128)*(Ss/128), 256, 0, stream>>>(xkb, e1t + (size_t)l * Ss * Hh,
        MKk/128, Ss, Hh, nullptr, nullptr, hbuf, t2i, (long long)LEe * Ss * Hh);
    gemm2<1><<<(MKk/128)*(Hh/128), 256, 0, stream>>>(hbuf, e2t + (size_t)l * Hh * Ss,
        MKk/128, Hh, Ss, xk, xk, xkb, t2i, (long long)LEe * Hh * Ss);
  }
  k_combine<<<Mm, 256, 0, stream>>>(x, xk, t2w);

  // RMSNorm -> bf16, then head GEMM (8-phase 256^2, swizzled)
  k_rmsnorm<<<Mm, 256, 0, stream>>>(x, nw, xb);
  gemm256<<<(Mm/256)*(Vv/256), 512, 0, stream>>>(xb, hwb, Mm/256, Vv, Hh, out);
}